// Round 7
// baseline (155.431 us; speedup 1.0000x reference)
//
#include <hip/hip_runtime.h>
#include <cmath>

// ProtICU on MI355X — round 7: R6's occupancy (512 thr, 2 blk/CU = 4 waves/SIMD)
// + R5's fully-unrolled nested conv_k (constant indices -> compiler batches
// A-loads ahead of MFMAs). Wave = 2 m-frags x {NJ=6/3/1}; acc<=48 VGPR.
// Pipeline per block (b, u of 16 final pos): stage x halo (196 rows, f32->bf16,
// stride 84) -> conv1 -> h1 (84 rows LDS) -> conv2 -> h2 (40 rows, aliases x)
// -> conv3 -> f (16 rows) -> head GEMMs -> prototype distances -> atomicMin.
// All GEMMs v_mfma_f32_16x16x32_bf16, fp32 acc. A-frags pre-packed lane-exact.

typedef __attribute__((ext_vector_type(8))) short short8;
typedef __attribute__((ext_vector_type(4))) float f32x4;

__device__ __forceinline__ unsigned short f2bf(float v) {
    union { float f; unsigned u; } x; x.f = v;
    unsigned r = x.u + 0x7fffu + ((x.u >> 16) & 1u);   // RNE
    return (unsigned short)(r >> 16);
}
__device__ __forceinline__ float bf2f(unsigned short b) {
    union { unsigned u; float f; } x; x.u = ((unsigned)b) << 16;
    return x.f;
}

// ---------------------------------------------------------------------------
// Weight packing into MFMA A-fragment order (16x16x32):
// lane holds A[m = mf*16 + (lane&15)][k = cc*32 + (lane>>4)*8 + j]
// conv: dst[((cc*5+kk)*8+mf)*64+lane][8] = W[m][c][kk]   (c >= C -> 0)
// mat : dst[((cc)*8+mf)*64+lane][8] = M[m][c]
// ---------------------------------------------------------------------------
__device__ void pack_conv_w(int t, int total, const float* __restrict__ W, int C,
                            unsigned short* __restrict__ dst)
{
    if (t >= total) return;
    int lane = t & 63, rest = t >> 6;
    int mf = rest & 7; rest >>= 3;
    int kk = rest % 5, cc = rest / 5;
    int m = mf * 16 + (lane & 15);
    int cb = cc * 32 + (lane >> 4) * 8;
    unsigned short v[8];
#pragma unroll
    for (int j = 0; j < 8; ++j) {
        int c = cb + j;
        v[j] = (c < C) ? f2bf(W[((size_t)m * C + c) * 5 + kk]) : (unsigned short)0;
    }
    *(uint4*)&dst[(size_t)t * 8] = *(uint4*)v;
}

__device__ void pack_mat(int t, const float* __restrict__ M, unsigned short* __restrict__ dst)
{
    if (t >= 2048) return;
    int lane = t & 63, mf = (t >> 6) & 7, cc = t >> 9;
    int m = mf * 16 + (lane & 15);
    int c0 = cc * 32 + (lane >> 4) * 8;
    unsigned short v[8];
#pragma unroll
    for (int j = 0; j < 8; ++j) v[j] = f2bf(M[(size_t)m * 128 + c0 + j]);
    *(uint4*)&dst[(size_t)t * 8] = *(uint4*)v;
}

__global__ __launch_bounds__(256)
void prep_weights_kernel(const float* __restrict__ W1, const float* __restrict__ W2,
                         const float* __restrict__ W3, const float* __restrict__ Wo1,
                         const float* __restrict__ Wo2, const float* __restrict__ protos,
                         unsigned short* A1, unsigned short* A2, unsigned short* A3,
                         unsigned short* AW1, unsigned short* AW2, unsigned short* AP,
                         float* pn, unsigned* pm_bits)
{
    int t = blockIdx.x * 256 + threadIdx.x;
    switch (blockIdx.y) {
    case 0: pack_conv_w(t, 7680,  W1, 76,  A1); break;
    case 1: pack_conv_w(t, 10240, W2, 128, A2); break;
    case 2: pack_conv_w(t, 10240, W3, 128, A3); break;
    case 3: pack_mat(t, Wo1, AW1); break;
    case 4: pack_mat(t, Wo2, AW2); break;
    case 5: pack_mat(t, protos, AP); break;
    case 6:
        if (t < 128) {
            float s = 0.f;
            for (int d = 0; d < 128; ++d) {
                float v = bf2f(f2bf(protos[(size_t)t * 128 + d]));
                s = fmaf(v, v, s);
            }
            pn[t] = s;
        }
        break;
    case 7:
        if (t < 4096) pm_bits[t] = 0x7F800000u;   // +inf init for atomicMin
        break;
    }
}

// ---------------------------------------------------------------------------
// Conv K-loop: wave = 2 m-frags (mf0, mf0+1) x NJ*16 rows at nbase.
// Fully-unrolled nested (cc, kk) loops — all offsets compile-time constant.
// B row (local) = nbase + j*16 + lc + kk, clamped to ROWMAX if >= 0.
// ---------------------------------------------------------------------------
template <int NJ, int NCC, int STRIDE, int ROWMAX>
__device__ __forceinline__ void conv_k(const unsigned short* __restrict__ Af,
                                       const unsigned short* __restrict__ sIn,
                                       int nbase, int mf0, int lane,
                                       f32x4 (&acc)[2][NJ])
{
    const int lc = lane & 15;
    const int lk = (lane >> 4) * 8;
#pragma unroll
    for (int i = 0; i < 2; ++i)
#pragma unroll
        for (int j = 0; j < NJ; ++j) acc[i][j] = (f32x4){0.f, 0.f, 0.f, 0.f};

#pragma unroll
    for (int cc = 0; cc < NCC; ++cc) {
#pragma unroll
        for (int kk = 0; kk < 5; ++kk) {
            const int step = cc * 5 + kk;
            short8 a[2];
#pragma unroll
            for (int i = 0; i < 2; ++i)
                a[i] = *(const short8*)&Af[(((size_t)step * 8 + mf0 + i) * 64 + lane) * 8];
            short8 bb[NJ];
#pragma unroll
            for (int j = 0; j < NJ; ++j) {
                int row = nbase + j * 16 + lc + kk;
                if (ROWMAX >= 0) row = min(row, ROWMAX);
                bb[j] = *(const short8*)&sIn[row * STRIDE + cc * 32 + lk];
            }
#pragma unroll
            for (int j = 0; j < NJ; ++j)
#pragma unroll
                for (int i = 0; i < 2; ++i)
                    acc[i][j] = __builtin_amdgcn_mfma_f32_16x16x32_bf16(a[i], bb[j], acc[i][j], 0, 0, 0);
        }
    }
}

// 1x1 GEMM over the 16 head positions; wave owns 1 m-frag (mf).
__device__ __forceinline__ void gemm_head(const unsigned short* __restrict__ Af,
                                          const unsigned short* __restrict__ s_f,
                                          int mf, int lane, f32x4& acc)
{
    const int lc = lane & 15;
    const int lk = (lane >> 4) * 8;
    acc = (f32x4){0.f, 0.f, 0.f, 0.f};
#pragma unroll
    for (int cc = 0; cc < 4; ++cc) {
        short8 a = *(const short8*)&Af[(((size_t)cc * 8 + mf) * 64 + lane) * 8];
        short8 bb = *(const short8*)&s_f[lc * 136 + cc * 32 + lk];
        acc = __builtin_amdgcn_mfma_f32_16x16x32_bf16(a, bb, acc, 0, 0, 0);
    }
}

// ---------------------------------------------------------------------------
// Megakernel: block = (u, b), 512 threads = 8 waves = 4 mg x 2 ng.
// ---------------------------------------------------------------------------
__global__ __launch_bounds__(512, 4)
void mega_kernel(const float* __restrict__ x,
                 const unsigned short* __restrict__ A1, const float* __restrict__ b1,
                 const unsigned short* __restrict__ A2, const float* __restrict__ b2,
                 const unsigned short* __restrict__ A3, const float* __restrict__ b3,
                 const unsigned short* __restrict__ AW1, const float* __restrict__ bo1,
                 const unsigned short* __restrict__ AW2, const float* __restrict__ bo2,
                 const unsigned short* __restrict__ AP,  const float* __restrict__ pn,
                 unsigned* __restrict__ pm_bits)
{
    __shared__ __align__(16) unsigned short s_x[196 * 84 + 16];  // x rows [128u-14,128u+182), stride 84 + guard
    __shared__ __align__(16) unsigned short s_h1[84 * 136];      // h1 rows [64u-6, 64u+78)
    __shared__ float s_cb[768];      // b1|b2|b3|bo1|bo2|pn
    __shared__ float s_part[64];
    __shared__ float s_fn[16];
    unsigned short* s_h2 = s_x;          // 40*136 = 5440 shorts (x dead after conv1)
    unsigned short* s_f  = s_x + 5440;   // 16*136 = 2176 shorts

    const int tid  = threadIdx.x;
    const int u    = blockIdx.x;    // 0..15
    const int b    = blockIdx.y;    // 0..31
    const int lane = tid & 63;
    const int wid  = tid >> 6;      // 0..7
    const int mg   = wid & 3;       // m-group: frags {2mg, 2mg+1} (oc 32mg..32mg+31)
    const int ng   = wid >> 2;      // n-group 0/1
    const int mf0  = mg * 2;
    const int lc   = lane & 15;
    const int lq   = (lane >> 4) * 4;

    // ---- stage biases + pn; zero the x-tile guard tail ----
    for (int i = tid; i < 768; i += 512) {
        const float* src = (i < 128) ? b1 : (i < 256) ? b2 : (i < 384) ? b3
                         : (i < 512) ? bo1 : (i < 640) ? bo2 : pn;
        s_cb[i] = src[i & 127];
    }
    if (tid < 16) s_x[196 * 84 + tid] = 0;

    // ---- stage x: rows l in [128u-14, 128u+182), f32 -> bf16, 84-short rows ----
    // (bf16 channels 76..83 zero; K-chunk cc=2 reads cols 64..95: cols >=84 land in
    //  the next row / guard and multiply zero-padded A1 weights -> contribute 0.)
    const int xbase = 128 * u - 14;
    for (int idx = tid; idx < 196 * 21; idx += 512) {
        int pos = idx / 21, c0 = (idx % 21) * 4;
        int l = xbase + pos;
        unsigned short v[4] = {0, 0, 0, 0};
        if (c0 < 76 && l >= 0 && l < 2048) {
            float4 xv = *(const float4*)&x[((size_t)b * 2048 + l) * 76 + c0];
            v[0] = f2bf(xv.x); v[1] = f2bf(xv.y); v[2] = f2bf(xv.z); v[3] = f2bf(xv.w);
        }
        *(uint2*)&s_x[pos * 84 + c0] = *(uint2*)v;
    }
    __syncthreads();

    // ============ conv1: c1 rows [128u-12, 128u+180), ng owns 96, NJ=6 ========
    {
        f32x4 acc[2][6];
        conv_k<6, 3, 84, -1>(A1, s_x, ng * 96, mf0, lane, acc);

        // bias+relu+pool2 -> s_h1 local r = nl/2 (global jg = 64u-6+r), keep r<84
#pragma unroll
        for (int i = 0; i < 2; ++i) {
            const int ch0 = (mf0 + i) * 16 + lq;
#pragma unroll
            for (int j = 0; j < 6; ++j) {
                const int nl = ng * 96 + j * 16 + lc;
                unsigned short pk[4];
#pragma unroll
                for (int r = 0; r < 4; ++r) {
                    float v = fmaxf(acc[i][j][r] + s_cb[ch0 + r], 0.f);
                    float o = __shfl_xor(v, 1);
                    pk[r] = f2bf(fmaxf(v, o));
                }
                if ((lc & 1) == 0) {
                    int rr = nl >> 1;
                    int jg = 64 * u - 6 + rr;
                    if (rr < 84) {
                        uint2 val = (jg >= 0 && jg < 1024) ? *(uint2*)pk : make_uint2(0u, 0u);
                        *(uint2*)&s_h1[rr * 136 + ch0] = val;
                    }
                }
            }
        }
    }
    __syncthreads();   // h1 complete; s_x dead -> s_h2/s_f reusable

    // ============ conv2: c2 rows [64u-4, 64u+92), ng owns 48, NJ=3, clamp<=83 ==
    {
        f32x4 acc[2][3];
        conv_k<3, 4, 136, 83>(A2, s_h1, ng * 48, mf0, lane, acc);

#pragma unroll
        for (int i = 0; i < 2; ++i) {
            const int ch0 = (mf0 + i) * 16 + lq;
#pragma unroll
            for (int j = 0; j < 3; ++j) {
                const int nl = ng * 48 + j * 16 + lc;
                unsigned short pk[4];
#pragma unroll
                for (int r = 0; r < 4; ++r) {
                    float v = fmaxf(acc[i][j][r] + s_cb[128 + ch0 + r], 0.f);
                    float o = __shfl_xor(v, 1);
                    pk[r] = f2bf(fmaxf(v, o));
                }
                if ((lc & 1) == 0) {
                    int rr = nl >> 1;             // h2 local, global jg = 32u-2+rr
                    int jg = 32 * u - 2 + rr;
                    if (rr < 40) {
                        uint2 val = (jg >= 0 && jg < 512) ? *(uint2*)pk : make_uint2(0u, 0u);
                        *(uint2*)&s_h2[rr * 136 + ch0] = val;
                    }
                }
            }
        }
    }
    __syncthreads();   // h2 complete

    // ============ conv3: c3 rows [32u, 32u+32), ng owns 16, NJ=1 ==============
    {
        f32x4 acc[2][1];
        conv_k<1, 4, 136, -1>(A3, s_h2, ng * 16, mf0, lane, acc);

#pragma unroll
        for (int i = 0; i < 2; ++i) {
            const int ch0 = (mf0 + i) * 16 + lq;
            const int nl = ng * 16 + lc;
            unsigned short pk[4];
#pragma unroll
            for (int r = 0; r < 4; ++r) {
                float v = fmaxf(acc[i][0][r] + s_cb[256 + ch0 + r], 0.f);
                float o = __shfl_xor(v, 1);
                pk[r] = f2bf(fmaxf(v, o));
            }
            if ((lc & 1) == 0)
                *(uint2*)&s_f[(nl >> 1) * 136 + ch0] = *(uint2*)pk;
        }
    }
    __syncthreads();   // f complete (16 positions x 128 ch)

    // ============ head: wave owns 1 m-frag (mf = wid) =========================
    f32x4 hacc;

    gemm_head(AW1, s_f, wid, lane, hacc);      // t1 = relu(Wo1 f + bo1)
    __syncthreads();
    {
        const int ch0 = wid * 16 + lq;
        unsigned short pk[4];
#pragma unroll
        for (int r = 0; r < 4; ++r)
            pk[r] = f2bf(fmaxf(hacc[r] + s_cb[384 + ch0 + r], 0.f));
        *(uint2*)&s_f[lc * 136 + ch0] = *(uint2*)pk;
    }
    __syncthreads();

    gemm_head(AW2, s_f, wid, lane, hacc);      // t2 = relu(Wo2 t1 + bo2)
    __syncthreads();
    {
        const int ch0 = wid * 16 + lq;
        unsigned short pk[4];
#pragma unroll
        for (int r = 0; r < 4; ++r)
            pk[r] = f2bf(fmaxf(hacc[r] + s_cb[512 + ch0 + r], 0.f));
        *(uint2*)&s_f[lc * 136 + ch0] = *(uint2*)pk;
    }
    __syncthreads();

    // fn[n] = ||t2[n]||^2, n in [0,16)
    if (tid < 64) {
        int n = tid >> 2, part = tid & 3;
        float s = 0.f;
        for (int c = part * 32; c < part * 32 + 32; ++c) {
            float v = bf2f(s_f[n * 136 + c]);
            s = fmaf(v, v, s);
        }
        s_part[part * 16 + n] = s;
    }
    __syncthreads();
    if (tid < 16)
        s_fn[tid] = s_part[tid] + s_part[16 + tid] + s_part[32 + tid] + s_part[48 + tid];
    __syncthreads();

    gemm_head(AP, s_f, wid, lane, hacc);       // dot = P t2

#pragma unroll
    for (int r = 0; r < 4; ++r) {
        const int p = wid * 16 + lq + r;
        float d2 = s_fn[lc] + s_cb[640 + p] - 2.f * hacc[r];
        float m = sqrtf(fmaxf(d2, 1e-12f));
#pragma unroll
        for (int s = 1; s < 16; s <<= 1)
            m = fminf(m, __shfl_xor(m, s));
        if (lc == 0)
            atomicMin(&pm_bits[(size_t)b * 128 + p], __float_as_uint(m));
    }
}

// ---------------------------------------------------------------------------
__global__ __launch_bounds__(128)
void finalize_kernel(const float* __restrict__ pm,       // (32,128) global min
                     const int* __restrict__ classes,
                     float* __restrict__ out)            // [64 sigmoid][4096 min_dis]
{
    __shared__ float r0[128], r1[128];
    const int b = blockIdx.x, p = threadIdx.x;
    float m = pm[(size_t)b * 128 + p];
    out[64 + b * 128 + p] = m;

    float sim = logf((m + 1.0f) / (m + 1e-4f));
    int cls = classes[p];
    r0[p] = (cls == 0) ? sim : -0.5f * sim;
    r1[p] = (cls == 1) ? sim : -0.5f * sim;
    __syncthreads();
    for (int s = 64; s > 0; s >>= 1) {
        if (p < s) { r0[p] += r0[p + s]; r1[p] += r1[p + s]; }
        __syncthreads();
    }
    if (p == 0) {
        out[b * 2 + 0] = 1.f / (1.f + expf(-r0[0]));
        out[b * 2 + 1] = 1.f / (1.f + expf(-r1[0]));
    }
}

// ---------------------------------------------------------------------------
extern "C" void kernel_launch(void* const* d_in, const int* in_sizes, int n_in,
                              void* d_out, int out_size, void* d_ws, size_t ws_size,
                              hipStream_t stream)
{
    (void)in_sizes; (void)n_in; (void)out_size; (void)ws_size;
    const float* x    = (const float*)d_in[0];
    const float* W1   = (const float*)d_in[1];
    const float* b1   = (const float*)d_in[2];
    const float* W2   = (const float*)d_in[3];
    const float* b2   = (const float*)d_in[4];
    const float* W3   = (const float*)d_in[5];
    const float* b3   = (const float*)d_in[6];
    const float* Wo1  = (const float*)d_in[7];
    const float* bo1  = (const float*)d_in[8];
    const float* Wo2  = (const float*)d_in[9];
    const float* bo2  = (const float*)d_in[10];
    const float* prot = (const float*)d_in[11];
    const int*   cls  = (const int*)d_in[12];
    float* out = (float*)d_out;

    // ws: A-fragments + pn + pm only (~566 KB)
    char* ws = (char*)d_ws;
    unsigned short* A1  = (unsigned short*)(ws);
    unsigned short* A2  = (unsigned short*)(ws + 122880);
    unsigned short* A3  = (unsigned short*)(ws + 286720);
    unsigned short* AW1 = (unsigned short*)(ws + 450560);
    unsigned short* AW2 = (unsigned short*)(ws + 483328);
    unsigned short* AP  = (unsigned short*)(ws + 516096);
    float*          pn  = (float*)(ws + 548864);
    unsigned*       pm  = (unsigned*)(ws + 549376);

    prep_weights_kernel<<<dim3(40, 8), 256, 0, stream>>>(W1, W2, W3, Wo1, Wo2, prot,
                                                         A1, A2, A3, AW1, AW2, AP, pn, pm);
    mega_kernel<<<dim3(16, 32), 512, 0, stream>>>(x, A1, b1, A2, b2, A3, b3,
                                                  AW1, bo1, AW2, bo2, AP, pn, pm);
    finalize_kernel<<<32, 128, 0, stream>>>((const float*)pm, cls, out);
}

// Round 8
// 139.701 us; speedup vs baseline: 1.1126x; 1.1126x over previous
//
#include <hip/hip_runtime.h>
#include <cmath>

// ProtICU on MI355X — round 8: small independent blocks, high intensity.
// Block = (batch b, chunk u of 8 final positions). Grid 32x32=1024, 256 thr =
// 4 waves. LDS ~31 KB -> 4 blocks/CU = 4 waves/SIMD in INDEPENDENT blocks
// (barrier stalls only 1/4 of resident waves). conv1 keeps NM=4 m-frags/wave
// (64 FLOP per LDS byte -> MFMA-bound); conv2/3 NM=2 (small phases).
// Pipeline: stage x halo (92 rows, f32->bf16, stride 84) -> conv1 -> h1 (44
// rows LDS) -> conv2 -> h2 (20 rows, aliases dead x) -> conv3 -> f (8 rows,
// padded to 16 with masking) -> head GEMMs -> distances -> atomicMin.
// All GEMMs v_mfma_f32_16x16x32_bf16, fp32 acc. A-frags pre-packed lane-exact.

typedef __attribute__((ext_vector_type(8))) short short8;
typedef __attribute__((ext_vector_type(4))) float f32x4;

__device__ __forceinline__ unsigned short f2bf(float v) {
    union { float f; unsigned u; } x; x.f = v;
    unsigned r = x.u + 0x7fffu + ((x.u >> 16) & 1u);   // RNE
    return (unsigned short)(r >> 16);
}
__device__ __forceinline__ float bf2f(unsigned short b) {
    union { unsigned u; float f; } x; x.u = ((unsigned)b) << 16;
    return x.f;
}

// ---------------------------------------------------------------------------
// Weight packing into MFMA A-fragment order (16x16x32):
// lane holds A[m = mf*16 + (lane&15)][k = cc*32 + (lane>>4)*8 + j]
// conv: dst[((cc*5+kk)*8+mf)*64+lane][8] = W[m][c][kk]   (c >= C -> 0)
// mat : dst[((cc)*8+mf)*64+lane][8] = M[m][c]
// ---------------------------------------------------------------------------
__device__ void pack_conv_w(int t, int total, const float* __restrict__ W, int C,
                            unsigned short* __restrict__ dst)
{
    if (t >= total) return;
    int lane = t & 63, rest = t >> 6;
    int mf = rest & 7; rest >>= 3;
    int kk = rest % 5, cc = rest / 5;
    int m = mf * 16 + (lane & 15);
    int cb = cc * 32 + (lane >> 4) * 8;
    unsigned short v[8];
#pragma unroll
    for (int j = 0; j < 8; ++j) {
        int c = cb + j;
        v[j] = (c < C) ? f2bf(W[((size_t)m * C + c) * 5 + kk]) : (unsigned short)0;
    }
    *(uint4*)&dst[(size_t)t * 8] = *(uint4*)v;
}

__device__ void pack_mat(int t, const float* __restrict__ M, unsigned short* __restrict__ dst)
{
    if (t >= 2048) return;
    int lane = t & 63, mf = (t >> 6) & 7, cc = t >> 9;
    int m = mf * 16 + (lane & 15);
    int c0 = cc * 32 + (lane >> 4) * 8;
    unsigned short v[8];
#pragma unroll
    for (int j = 0; j < 8; ++j) v[j] = f2bf(M[(size_t)m * 128 + c0 + j]);
    *(uint4*)&dst[(size_t)t * 8] = *(uint4*)v;
}

__global__ __launch_bounds__(256)
void prep_weights_kernel(const float* __restrict__ W1, const float* __restrict__ W2,
                         const float* __restrict__ W3, const float* __restrict__ Wo1,
                         const float* __restrict__ Wo2, const float* __restrict__ protos,
                         unsigned short* A1, unsigned short* A2, unsigned short* A3,
                         unsigned short* AW1, unsigned short* AW2, unsigned short* AP,
                         float* pn, unsigned* pm_bits)
{
    int t = blockIdx.x * 256 + threadIdx.x;
    switch (blockIdx.y) {
    case 0: pack_conv_w(t, 7680,  W1, 76,  A1); break;
    case 1: pack_conv_w(t, 10240, W2, 128, A2); break;
    case 2: pack_conv_w(t, 10240, W3, 128, A3); break;
    case 3: pack_mat(t, Wo1, AW1); break;
    case 4: pack_mat(t, Wo2, AW2); break;
    case 5: pack_mat(t, protos, AP); break;
    case 6:
        if (t < 128) {
            float s = 0.f;
            for (int d = 0; d < 128; ++d) {
                float v = bf2f(f2bf(protos[(size_t)t * 128 + d]));
                s = fmaf(v, v, s);
            }
            pn[t] = s;
        }
        break;
    case 7:
        if (t < 4096) pm_bits[t] = 0x7F800000u;   // +inf init for atomicMin
        break;
    }
}

// ---------------------------------------------------------------------------
// Conv K-loop: wave = NM m-frags (mf0..mf0+NM-1) x NJ*16 rows at nbase.
// Fully unrolled (cc, kk) — constant offsets. B row = nbase+j*16+lc+kk,
// clamped to ROWMAX if >= 0.
// ---------------------------------------------------------------------------
template <int NM, int NJ, int NCC, int STRIDE, int ROWMAX>
__device__ __forceinline__ void conv_k(const unsigned short* __restrict__ Af,
                                       const unsigned short* __restrict__ sIn,
                                       int nbase, int mf0, int lane,
                                       f32x4 (&acc)[NM][NJ])
{
    const int lc = lane & 15;
    const int lk = (lane >> 4) * 8;
#pragma unroll
    for (int i = 0; i < NM; ++i)
#pragma unroll
        for (int j = 0; j < NJ; ++j) acc[i][j] = (f32x4){0.f, 0.f, 0.f, 0.f};

#pragma unroll
    for (int cc = 0; cc < NCC; ++cc) {
#pragma unroll
        for (int kk = 0; kk < 5; ++kk) {
            const int step = cc * 5 + kk;
            short8 a[NM];
#pragma unroll
            for (int i = 0; i < NM; ++i)
                a[i] = *(const short8*)&Af[(((size_t)step * 8 + mf0 + i) * 64 + lane) * 8];
            short8 bb[NJ];
#pragma unroll
            for (int j = 0; j < NJ; ++j) {
                int row = nbase + j * 16 + lc + kk;
                if (ROWMAX >= 0) row = min(row, ROWMAX);
                bb[j] = *(const short8*)&sIn[row * STRIDE + cc * 32 + lk];
            }
#pragma unroll
            for (int j = 0; j < NJ; ++j)
#pragma unroll
                for (int i = 0; i < NM; ++i)
                    acc[i][j] = __builtin_amdgcn_mfma_f32_16x16x32_bf16(a[i], bb[j], acc[i][j], 0, 0, 0);
        }
    }
}

// 1x1 GEMM over 16 head rows in s_f; wave owns 2 m-frags (mf0h, mf0h+1).
__device__ __forceinline__ void gemm_head(const unsigned short* __restrict__ Af,
                                          const unsigned short* __restrict__ s_f,
                                          int mf0h, int lane, f32x4 (&acc)[2])
{
    const int lc = lane & 15;
    const int lk = (lane >> 4) * 8;
    acc[0] = (f32x4){0.f, 0.f, 0.f, 0.f};
    acc[1] = (f32x4){0.f, 0.f, 0.f, 0.f};
#pragma unroll
    for (int cc = 0; cc < 4; ++cc) {
        short8 a[2];
#pragma unroll
        for (int i = 0; i < 2; ++i)
            a[i] = *(const short8*)&Af[(((size_t)cc * 8 + mf0h + i) * 64 + lane) * 8];
        short8 bb = *(const short8*)&s_f[lc * 136 + cc * 32 + lk];
#pragma unroll
        for (int i = 0; i < 2; ++i)
            acc[i] = __builtin_amdgcn_mfma_f32_16x16x32_bf16(a[i], bb, acc[i], 0, 0, 0);
    }
}

// ---------------------------------------------------------------------------
// Megakernel: block = (u, b), 256 threads = 4 waves.
// conv1: 2 mg x 2 ng, wave NM=4 x NJ=3. conv2: 4 waves NM=2 x NJ=3.
// conv3: 4 waves NM=2 x NJ=1. head: wave = frags {2wid, 2wid+1}.
// ---------------------------------------------------------------------------
__global__ __launch_bounds__(256, 4)
void mega_kernel(const float* __restrict__ x,
                 const unsigned short* __restrict__ A1, const float* __restrict__ b1,
                 const unsigned short* __restrict__ A2, const float* __restrict__ b2,
                 const unsigned short* __restrict__ A3, const float* __restrict__ b3,
                 const unsigned short* __restrict__ AW1, const float* __restrict__ bo1,
                 const unsigned short* __restrict__ AW2, const float* __restrict__ bo2,
                 const unsigned short* __restrict__ AP,  const float* __restrict__ pn,
                 unsigned* __restrict__ pm_bits)
{
    __shared__ __align__(16) unsigned short s_x[92 * 84 + 16];  // x rows [64u-14, 64u+78)
    __shared__ __align__(16) unsigned short s_h1[44 * 136];     // h1 rows [32u-6, 32u+38)
    __shared__ float s_cb[768];      // b1|b2|b3|bo1|bo2|pn
    __shared__ float s_part[64];
    __shared__ float s_fn[16];
    unsigned short* s_h2 = s_x;          // 20*136 = 2720 shorts (x dead after conv1)
    unsigned short* s_f  = s_x + 2720;   // 16*136 = 2176 shorts (rows 8..15 pad)

    const int tid  = threadIdx.x;
    const int u    = blockIdx.x;    // 0..31
    const int b    = blockIdx.y;    // 0..31
    const int lane = tid & 63;
    const int wid  = tid >> 6;      // 0..3
    const int lc   = lane & 15;
    const int lq   = (lane >> 4) * 4;

    // ---- stage biases + pn; zero x guard ----
    for (int i = tid; i < 768; i += 256) {
        const float* src = (i < 128) ? b1 : (i < 256) ? b2 : (i < 384) ? b3
                         : (i < 512) ? bo1 : (i < 640) ? bo2 : pn;
        s_cb[i] = src[i & 127];
    }
    if (tid < 16) s_x[92 * 84 + tid] = 0;

    // ---- stage x: rows l in [64u-14, 64u+78), f32 -> bf16, 84-short rows ----
    const int xbase = 64 * u - 14;
    for (int idx = tid; idx < 92 * 21; idx += 256) {
        int pos = idx / 21, c0 = (idx % 21) * 4;
        int l = xbase + pos;
        unsigned short v[4] = {0, 0, 0, 0};
        if (c0 < 76 && l >= 0 && l < 2048) {
            float4 xv = *(const float4*)&x[((size_t)b * 2048 + l) * 76 + c0];
            v[0] = f2bf(xv.x); v[1] = f2bf(xv.y); v[2] = f2bf(xv.z); v[3] = f2bf(xv.w);
        }
        *(uint2*)&s_x[pos * 84 + c0] = *(uint2*)v;
    }
    __syncthreads();

    // ============ conv1: c1 local n in [0,96) <-> global 64u-12+n =============
    // 2 mg x 2 ng; wave NM=4 (oc 64mg..64mg+63) x NJ=3 (rows ng*48..+48).
    {
        const int mg = wid & 1, ng = wid >> 1;
        const int mf0 = mg * 4;
        f32x4 acc[4][3];
        conv_k<4, 3, 3, 84, 91>(A1, s_x, ng * 48, mf0, lane, acc);

        // bias+relu+pool2 -> s_h1 rr = n>>1 (global jg = 32u-6+rr), keep rr<44
#pragma unroll
        for (int i = 0; i < 4; ++i) {
            const int ch0 = (mf0 + i) * 16 + lq;
#pragma unroll
            for (int j = 0; j < 3; ++j) {
                const int nl = ng * 48 + j * 16 + lc;
                unsigned short pk[4];
#pragma unroll
                for (int r = 0; r < 4; ++r) {
                    float v = fmaxf(acc[i][j][r] + s_cb[ch0 + r], 0.f);
                    float o = __shfl_xor(v, 1);
                    pk[r] = f2bf(fmaxf(v, o));
                }
                if ((lc & 1) == 0) {
                    int rr = nl >> 1;
                    int jg = 32 * u - 6 + rr;
                    if (rr < 44) {
                        uint2 val = (jg >= 0 && jg < 1024) ? *(uint2*)pk : make_uint2(0u, 0u);
                        *(uint2*)&s_h1[rr * 136 + ch0] = val;
                    }
                }
            }
        }
    }
    __syncthreads();   // h1 complete; s_x dead -> s_h2/s_f reusable

    // ============ conv2: c2 local n in [0,48) <-> global 32u-4+n ==============
    // 4 waves NM=2 (oc 32wid..+31) x NJ=3 (all rows), clamp B row <= 43.
    {
        const int mf0 = wid * 2;
        f32x4 acc[2][3];
        conv_k<2, 3, 4, 136, 43>(A2, s_h1, 0, mf0, lane, acc);

#pragma unroll
        for (int i = 0; i < 2; ++i) {
            const int ch0 = (mf0 + i) * 16 + lq;
#pragma unroll
            for (int j = 0; j < 3; ++j) {
                const int nl = j * 16 + lc;
                unsigned short pk[4];
#pragma unroll
                for (int r = 0; r < 4; ++r) {
                    float v = fmaxf(acc[i][j][r] + s_cb[128 + ch0 + r], 0.f);
                    float o = __shfl_xor(v, 1);
                    pk[r] = f2bf(fmaxf(v, o));
                }
                if ((lc & 1) == 0) {
                    int rr = nl >> 1;             // h2 local, global jg2 = 16u-2+rr
                    int jg = 16 * u - 2 + rr;
                    if (rr < 20) {
                        uint2 val = (jg >= 0 && jg < 512) ? *(uint2*)pk : make_uint2(0u, 0u);
                        *(uint2*)&s_h2[rr * 136 + ch0] = val;
                    }
                }
            }
        }
    }
    __syncthreads();   // h2 complete

    // ============ conv3: c3 local n = lc in [0,16) <-> global 16u+n ===========
    // 4 waves NM=2 x NJ=1; B rows 0..19 exact.
    {
        const int mf0 = wid * 2;
        f32x4 acc[2][1];
        conv_k<2, 1, 4, 136, -1>(A3, s_h2, 0, mf0, lane, acc);

#pragma unroll
        for (int i = 0; i < 2; ++i) {
            const int ch0 = (mf0 + i) * 16 + lq;
            unsigned short pk[4];
#pragma unroll
            for (int r = 0; r < 4; ++r) {
                float v = fmaxf(acc[i][0][r] + s_cb[256 + ch0 + r], 0.f);
                float o = __shfl_xor(v, 1);
                pk[r] = f2bf(fmaxf(v, o));
            }
            if ((lc & 1) == 0)
                *(uint2*)&s_f[(lc >> 1) * 136 + ch0] = *(uint2*)pk;
        }
        // zero pad rows 8..15 of s_f (stale alias garbage otherwise)
        for (int i = tid; i < 544; i += 256)
            ((unsigned*)(s_f + 1088))[i] = 0u;
    }
    __syncthreads();   // f complete (rows 0..7 real, 8..15 zero)

    // ============ head: wave owns m-frags {2wid, 2wid+1} ======================
    const int mf0h = wid * 2;
    f32x4 hacc[2];

    gemm_head(AW1, s_f, mf0h, lane, hacc);     // t1 = relu(Wo1 f + bo1)
    __syncthreads();
#pragma unroll
    for (int i = 0; i < 2; ++i) {
        const int ch0 = (mf0h + i) * 16 + lq;
        unsigned short pk[4];
#pragma unroll
        for (int r = 0; r < 4; ++r)
            pk[r] = f2bf(fmaxf(hacc[i][r] + s_cb[384 + ch0 + r], 0.f));
        *(uint2*)&s_f[lc * 136 + ch0] = *(uint2*)pk;
    }
    __syncthreads();

    gemm_head(AW2, s_f, mf0h, lane, hacc);     // t2 = relu(Wo2 t1 + bo2)
    __syncthreads();
#pragma unroll
    for (int i = 0; i < 2; ++i) {
        const int ch0 = (mf0h + i) * 16 + lq;
        unsigned short pk[4];
#pragma unroll
        for (int r = 0; r < 4; ++r)
            pk[r] = f2bf(fmaxf(hacc[i][r] + s_cb[512 + ch0 + r], 0.f));
        *(uint2*)&s_f[lc * 136 + ch0] = *(uint2*)pk;
    }
    __syncthreads();

    // fn[n] = ||t2[n]||^2, n in [0,16) (pad rows included, masked later)
    if (tid < 64) {
        int n = tid >> 2, part = tid & 3;
        float s = 0.f;
        for (int c = part * 32; c < part * 32 + 32; ++c) {
            float v = bf2f(s_f[n * 136 + c]);
            s = fmaf(v, v, s);
        }
        s_part[part * 16 + n] = s;
    }
    __syncthreads();
    if (tid < 16)
        s_fn[tid] = s_part[tid] + s_part[16 + tid] + s_part[32 + tid] + s_part[48 + tid];
    __syncthreads();

    gemm_head(AP, s_f, mf0h, lane, hacc);      // dot = P t2

#pragma unroll
    for (int i = 0; i < 2; ++i) {
#pragma unroll
        for (int r = 0; r < 4; ++r) {
            const int p = (mf0h + i) * 16 + lq + r;
            float d2 = s_fn[lc] + s_cb[640 + p] - 2.f * hacc[i][r];
            float m = (lc < 8) ? sqrtf(fmaxf(d2, 1e-12f)) : 3.0e38f;  // mask pad cols
#pragma unroll
            for (int s = 1; s < 16; s <<= 1)
                m = fminf(m, __shfl_xor(m, s));
            if (lc == 0)
                atomicMin(&pm_bits[(size_t)b * 128 + p], __float_as_uint(m));
        }
    }
}

// ---------------------------------------------------------------------------
__global__ __launch_bounds__(128)
void finalize_kernel(const float* __restrict__ pm,       // (32,128) global min
                     const int* __restrict__ classes,
                     float* __restrict__ out)            // [64 sigmoid][4096 min_dis]
{
    __shared__ float r0[128], r1[128];
    const int b = blockIdx.x, p = threadIdx.x;
    float m = pm[(size_t)b * 128 + p];
    out[64 + b * 128 + p] = m;

    float sim = logf((m + 1.0f) / (m + 1e-4f));
    int cls = classes[p];
    r0[p] = (cls == 0) ? sim : -0.5f * sim;
    r1[p] = (cls == 1) ? sim : -0.5f * sim;
    __syncthreads();
    for (int s = 64; s > 0; s >>= 1) {
        if (p < s) { r0[p] += r0[p + s]; r1[p] += r1[p + s]; }
        __syncthreads();
    }
    if (p == 0) {
        out[b * 2 + 0] = 1.f / (1.f + expf(-r0[0]));
        out[b * 2 + 1] = 1.f / (1.f + expf(-r1[0]));
    }
}

// ---------------------------------------------------------------------------
extern "C" void kernel_launch(void* const* d_in, const int* in_sizes, int n_in,
                              void* d_out, int out_size, void* d_ws, size_t ws_size,
                              hipStream_t stream)
{
    (void)in_sizes; (void)n_in; (void)out_size; (void)ws_size;
    const float* x    = (const float*)d_in[0];
    const float* W1   = (const float*)d_in[1];
    const float* b1   = (const float*)d_in[2];
    const float* W2   = (const float*)d_in[3];
    const float* b2   = (const float*)d_in[4];
    const float* W3   = (const float*)d_in[5];
    const float* b3   = (const float*)d_in[6];
    const float* Wo1  = (const float*)d_in[7];
    const float* bo1  = (const float*)d_in[8];
    const float* Wo2  = (const float*)d_in[9];
    const float* bo2  = (const float*)d_in[10];
    const float* prot = (const float*)d_in[11];
    const int*   cls  = (const int*)d_in[12];
    float* out = (float*)d_out;

    // ws: A-fragments + pn + pm only (~566 KB)
    char* ws = (char*)d_ws;
    unsigned short* A1  = (unsigned short*)(ws);
    unsigned short* A2  = (unsigned short*)(ws + 122880);
    unsigned short* A3  = (unsigned short*)(ws + 286720);
    unsigned short* AW1 = (unsigned short*)(ws + 450560);
    unsigned short* AW2 = (unsigned short*)(ws + 483328);
    unsigned short* AP  = (unsigned short*)(ws + 516096);
    float*          pn  = (float*)(ws + 548864);
    unsigned*       pm  = (unsigned*)(ws + 549376);

    prep_weights_kernel<<<dim3(40, 8), 256, 0, stream>>>(W1, W2, W3, Wo1, Wo2, prot,
                                                         A1, A2, A3, AW1, AW2, AP, pn, pm);
    mega_kernel<<<dim3(32, 32), 256, 0, stream>>>(x, A1, b1, A2, b2, A3, b3,
                                                  AW1, bo1, AW2, bo2, AP, pn, pm);
    finalize_kernel<<<32, 128, 0, stream>>>((const float*)pm, cls, out);
}